// Round 27
// baseline (116.632 us; speedup 1.0000x reference)
//
#include <hip/hip_runtime.h>
#include <math.h>

#define N_NODES 50000
#define E_EDGES 800000
#define D_FEAT  64
#define C_CH    3
#define H_HID   8
#define OUT_F   128
#define CD      192              // C*D
#define NTILES  (N_NODES / 16)   // 3125 exact
#define XCVT_BLOCKS (N_NODES * D_FEAT / 4 / 256)   // 3125
#define EDGEB   ((E_EDGES + 1023) / 1024)          // 782 (4 edges/thread)
#define NBUCK   196              // buckets of 256 nodes (dst>>8)
#define BCAP    5120             // per-bucket capacity (mean 4096, +16 sigma)

typedef _Float16 half8 __attribute__((ext_vector_type(8)));
typedef _Float16 half4 __attribute__((ext_vector_type(4)));
typedef float f32x4 __attribute__((ext_vector_type(4)));

__device__ __forceinline__ float lrelu(float v) { return v >= 0.f ? v : 0.01f * v; }

__device__ __forceinline__ unsigned short f2h_bits(float f) {
    _Float16 h = (_Float16)f;
    unsigned short b;
    __builtin_memcpy(&b, &h, 2);
    return b;
}
__device__ __forceinline__ float h2f_bits(unsigned b) {
    unsigned short s = (unsigned short)b;
    _Float16 h;
    __builtin_memcpy(&h, &s, 2);
    return (float)h;
}

__device__ __forceinline__ float edge_mlp(
    float a, const float* __restrict__ w1, const float* __restrict__ b1,
    const float* __restrict__ w2, float b2c, int c)
{
    float s = 0.f;
#pragma unroll
    for (int h = 0; h < H_HID; ++h) {
        float t = fmaf(a, w1[c * H_HID + h], b1[c * H_HID + h]);
        t = (t >= 0.f) ? t : 0.01f * t;               // leaky_relu
        s = fmaf(t, w2[c * H_HID + h], s);
    }
    s += b2c;
    return (s > 0.f) ? s : expm1f(s);                 // elu
}

// --- K1: {edge MLP + coarse-bucket partition (LDS int hist)} + {x->f16} -----
__global__ __launch_bounds__(256) void k_part(
    const float* __restrict__ x, _Float16* __restrict__ xh,
    const int* __restrict__ ei, const float* __restrict__ ea,
    const float* __restrict__ w1, const float* __restrict__ b1,
    const float* __restrict__ w2, const float* __restrict__ b2,
    int* __restrict__ bcnt, uint2* __restrict__ brec,
    unsigned char* __restrict__ bd8)
{
    if (blockIdx.x >= EDGEB) {
        int i = (blockIdx.x - EDGEB) * 256 + threadIdx.x;
        float4 f = ((const float4*)x)[i];
        half4 h;
        h[0] = (_Float16)f.x; h[1] = (_Float16)f.y;
        h[2] = (_Float16)f.z; h[3] = (_Float16)f.w;
        *(half4*)(xh + (size_t)i * 4) = h;
        return;
    }
    __shared__ int hist[256];
    __shared__ int gbase[256];

    const int tid = threadIdx.x;
    const int e0  = blockIdx.x * 1024 + tid * 4;
    const int* dstp = ei + E_EDGES;
    const float b20 = b2[0], b21 = b2[1], b22 = b2[2];

    hist[tid] = 0;
    __syncthreads();

    int   sv[4], de[4];
    float av[4];
    if (e0 + 3 < E_EDGES) {
        int4   s4 = *(const int4*)(ei + e0);
        int4   d4 = *(const int4*)(dstp + e0);
        float4 a4 = *(const float4*)(ea + e0);
        sv[0]=s4.x; sv[1]=s4.y; sv[2]=s4.z; sv[3]=s4.w;
        de[0]=d4.x; de[1]=d4.y; de[2]=d4.z; de[3]=d4.w;
        av[0]=a4.x; av[1]=a4.y; av[2]=a4.z; av[3]=a4.w;
    } else {
#pragma unroll
        for (int j = 0; j < 4; ++j) {
            int e = e0 + j;
            sv[j] = (e < E_EDGES) ? ei[e]   : 0;
            de[j] = (e < E_EDGES) ? dstp[e] : -1;
            av[j] = (e < E_EDGES) ? ea[e]   : 0.f;
        }
    }

    int bk[4], lr[4];
#pragma unroll
    for (int j = 0; j < 4; ++j) {
        if (de[j] >= 0) {
            bk[j] = de[j] >> 8;
            lr[j] = atomicAdd(&hist[bk[j]], 1);   // native LDS int atomic
        } else bk[j] = -1;
    }
    __syncthreads();
    if (tid < NBUCK && hist[tid]) gbase[tid] = atomicAdd(bcnt + tid, hist[tid]);
    __syncthreads();

#pragma unroll
    for (int j = 0; j < 4; ++j) {
        if (bk[j] >= 0) {
            float w0 = edge_mlp(av[j], w1, b1, w2, b20, 0);
            float wA = edge_mlp(av[j], w1, b1, w2, b21, 1);
            float wB = edge_mlp(av[j], w1, b1, w2, b22, 2);
            uint2 r;
            r.x = (unsigned)sv[j] | ((unsigned)f2h_bits(w0) << 16);
            r.y = (unsigned)f2h_bits(wA) | ((unsigned)f2h_bits(wB) << 16);
            int pos = gbase[bk[j]] + lr[j];
            brec[(size_t)bk[j] * BCAP + pos] = r;
            bd8 [(size_t)bk[j] * BCAP + pos] = (unsigned char)(de[j] & 255);
        }
    }
}

// --- K2: per-bucket fine sort (LDS) + DIRECT offsets emission ---------------
__global__ __launch_bounds__(512) void k_sortb(
    const int* __restrict__ bcnt, const uint2* __restrict__ brec,
    const unsigned char* __restrict__ bd8,
    int* __restrict__ offsets, uint2* __restrict__ sorted)
{
    __shared__ int sc[256];
    __shared__ int nodeh[256];
    __shared__ int pfx[256];
    __shared__ int cursor[256];
    __shared__ unsigned char s8[BCAP];

    const int tid = threadIdx.x;
    const int b   = blockIdx.x;

    if (tid < 256) {
        sc[tid]    = (tid < NBUCK) ? bcnt[tid] : 0;
        nodeh[tid] = 0;
    }
    __syncthreads();
    for (int off = 1; off < 256; off <<= 1) {
        int t = 0;
        if (tid < 256 && tid >= off) t = sc[tid - off];
        __syncthreads();
        if (tid < 256) sc[tid] += t;
        __syncthreads();
    }
    const int base = (b == 0) ? 0 : sc[b - 1];
    const int cnt  = bcnt[b];

    for (int i = tid; i < cnt; i += 512) {
        unsigned char d = bd8[(size_t)b * BCAP + i];
        s8[i] = d;
        atomicAdd(&nodeh[d], 1);
    }
    __syncthreads();

    if (tid < 256) pfx[tid] = nodeh[tid];
    __syncthreads();
    for (int off = 1; off < 256; off <<= 1) {
        int t = 0;
        if (tid < 256 && tid >= off) t = pfx[tid - off];
        __syncthreads();
        if (tid < 256) pfx[tid] += t;
        __syncthreads();
    }
    if (tid < 256) {
        int excl = pfx[tid] - nodeh[tid];
        cursor[tid] = excl;
        int n = b * 256 + tid;
        if (n < N_NODES) offsets[n] = base + excl;   // coalesced
    }
    __syncthreads();

    for (int i = tid; i < cnt; i += 512) {
        uint2 r = brec[(size_t)b * BCAP + i];
        int pos = atomicAdd(&cursor[s8[i]], 1);
        sorted[base + pos] = r;
    }
}

// --- K3: gather, 2 nodes/wave, 4 chains/node = 8 outstanding gathers/wave ---
__global__ __launch_bounds__(256) void k_gather(
    const uint2* __restrict__ sorted, const int* __restrict__ offsets,
    const _Float16* __restrict__ xh, const float* __restrict__ eps,
    _Float16* __restrict__ v)
{
    const int wid  = threadIdx.x >> 6;
    const int lane = threadIdx.x & 63;
    const int n0   = blockIdx.x * 8 + wid * 2;   // grid = N/8 = 6250 exact

    const int o0 = offsets[n0];
    const int o1 = offsets[n0 + 1];
    const int o2 = (n0 + 2 < N_NODES) ? offsets[n0 + 2] : E_EDGES;

    float xn0 = (float)xh[(size_t)n0 * D_FEAT + lane];
    float xn1 = (float)xh[(size_t)(n0 + 1) * D_FEAT + lane];

    float A[4][3];   // node0 chains
    float B[4][3];   // node1 chains
#pragma unroll
    for (int k = 0; k < 4; ++k)
#pragma unroll
        for (int c = 0; c < 3; ++c) { A[k][c] = 0.f; B[k][c] = 0.f; }

    int base0 = o0, base1 = o1;
    while (base0 < o1 || base1 < o2) {
        const int m0 = (base0 < o1) ? min(64, o1 - base0) : 0;
        const int m1 = (base1 < o2) ? min(64, o2 - base1) : 0;
        uint2 rec0 = make_uint2(0u, 0u), rec1 = make_uint2(0u, 0u);
        if (lane < m0) rec0 = sorted[base0 + lane];
        if (lane < m1) rec1 = sorted[base1 + lane];
        const int mm = max(m0, m1);
        for (int j = 0; j < mm; j += 4) {
#pragma unroll
            for (int k = 0; k < 4; ++k) {
                if (j + k < m0) {                       // wave-uniform branch
                    unsigned rx = (unsigned)__shfl((int)rec0.x, j + k);
                    unsigned ry = (unsigned)__shfl((int)rec0.y, j + k);
                    float xv = (float)xh[(size_t)(rx & 0xFFFFu) * D_FEAT + lane];
                    A[k][0] = fmaf(h2f_bits(rx >> 16),     xv, A[k][0]);
                    A[k][1] = fmaf(h2f_bits(ry & 0xFFFFu), xv, A[k][1]);
                    A[k][2] = fmaf(h2f_bits(ry >> 16),     xv, A[k][2]);
                }
            }
#pragma unroll
            for (int k = 0; k < 4; ++k) {
                if (j + k < m1) {                       // wave-uniform branch
                    unsigned rx = (unsigned)__shfl((int)rec1.x, j + k);
                    unsigned ry = (unsigned)__shfl((int)rec1.y, j + k);
                    float xv = (float)xh[(size_t)(rx & 0xFFFFu) * D_FEAT + lane];
                    B[k][0] = fmaf(h2f_bits(rx >> 16),     xv, B[k][0]);
                    B[k][1] = fmaf(h2f_bits(ry & 0xFFFFu), xv, B[k][1]);
                    B[k][2] = fmaf(h2f_bits(ry >> 16),     xv, B[k][2]);
                }
            }
        }
        base0 += 64; base1 += 64;
    }

    const float e0c = 1.f + eps[0], e1c = 1.f + eps[1], e2c = 1.f + eps[2];
    {
        float s0 = A[0][0] + A[1][0] + A[2][0] + A[3][0];
        float s1 = A[0][1] + A[1][1] + A[2][1] + A[3][1];
        float s2 = A[0][2] + A[1][2] + A[2][2] + A[3][2];
        _Float16* vr = v + (size_t)n0 * CD;
        vr[lane]       = (_Float16)(s0 + e0c * xn0);
        vr[64 + lane]  = (_Float16)(s1 + e1c * xn0);
        vr[128 + lane] = (_Float16)(s2 + e2c * xn0);
    }
    {
        float s0 = B[0][0] + B[1][0] + B[2][0] + B[3][0];
        float s1 = B[0][1] + B[1][1] + B[2][1] + B[3][1];
        float s2 = B[0][2] + B[1][2] + B[2][2] + B[3][2];
        _Float16* vr = v + (size_t)(n0 + 1) * CD;
        vr[lane]       = (_Float16)(s0 + e0c * xn1);
        vr[64 + lane]  = (_Float16)(s1 + e1c * xn1);
        vr[128 + lane] = (_Float16)(s2 + e2c * xn1);
    }
}

// --- K4: MLP1(lrelu) + MLP2 via f16 MFMA ------------------------------------
__global__ __launch_bounds__(256) void k_mlp(
    const _Float16* __restrict__ v,
    const float* __restrict__ nw1, const float* __restrict__ nb1,
    const float* __restrict__ nw2, const float* __restrict__ nb2,
    float* __restrict__ out)
{
    __shared__ _Float16 vtile[16][CD + 8];     // stride 400B (16B mult)
    __shared__ _Float16 htile[16][OUT_F + 8];  // stride 272B (16B mult)

    const int tid  = threadIdx.x;
    const int lane = tid & 63;
    const int wid  = tid >> 6;
    const int arow = lane & 15;
    const int kg   = lane >> 4;
    const int o0   = wid * 32;

    half8 w1f[6][2], w2f[4][2];
#pragma unroll
    for (int kk = 0; kk < 6; ++kk)
#pragma unroll
        for (int nt = 0; nt < 2; ++nt) {
            half8 f;
            int colb = o0 + nt * 16 + arow;
            int kb = kk * 32 + kg * 8;
#pragma unroll
            for (int j = 0; j < 8; ++j)
                f[j] = (_Float16)nw1[(size_t)(kb + j) * OUT_F + colb];
            w1f[kk][nt] = f;
        }
#pragma unroll
    for (int kk = 0; kk < 4; ++kk)
#pragma unroll
        for (int nt = 0; nt < 2; ++nt) {
            half8 f;
            int colb = o0 + nt * 16 + arow;
            int kb = kk * 32 + kg * 8;
#pragma unroll
            for (int j = 0; j < 8; ++j)
                f[j] = (_Float16)nw2[(size_t)(kb + j) * OUT_F + colb];
            w2f[kk][nt] = f;
        }

    const float b1a = nb1[o0 + arow],      b1b = nb1[o0 + 16 + arow];
    const float b2a = nb2[o0 + arow],      b2b = nb2[o0 + 16 + arow];

    for (int t = blockIdx.x; t < NTILES; t += gridDim.x) {
        const int nb16 = t * 16;
        __syncthreads();

        for (int i = tid; i < 16 * (CD / 8); i += 256) {    // 384 chunks
            int row = i / (CD / 8), c8 = i % (CD / 8);
            *(half8*)&vtile[row][c8 * 8] =
                *(const half8*)(v + (size_t)(nb16 + row) * CD + c8 * 8);
        }
        __syncthreads();

        f32x4 acc0 = {0.f, 0.f, 0.f, 0.f}, acc1 = {0.f, 0.f, 0.f, 0.f};
#pragma unroll
        for (int kk = 0; kk < 6; ++kk) {
            half8 a = *(const half8*)&vtile[arow][kk * 32 + kg * 8];
            acc0 = __builtin_amdgcn_mfma_f32_16x16x32_f16(a, w1f[kk][0], acc0, 0, 0, 0);
            acc1 = __builtin_amdgcn_mfma_f32_16x16x32_f16(a, w1f[kk][1], acc1, 0, 0, 0);
        }
#pragma unroll
        for (int r = 0; r < 4; ++r) {
            int hr = kg * 4 + r;
            htile[hr][o0 + arow]      = (_Float16)lrelu(acc0[r] + b1a);
            htile[hr][o0 + 16 + arow] = (_Float16)lrelu(acc1[r] + b1b);
        }
        __syncthreads();

        f32x4 c0 = {0.f, 0.f, 0.f, 0.f}, c1 = {0.f, 0.f, 0.f, 0.f};
#pragma unroll
        for (int kk = 0; kk < 4; ++kk) {
            half8 a = *(const half8*)&htile[arow][kk * 32 + kg * 8];
            c0 = __builtin_amdgcn_mfma_f32_16x16x32_f16(a, w2f[kk][0], c0, 0, 0, 0);
            c1 = __builtin_amdgcn_mfma_f32_16x16x32_f16(a, w2f[kk][1], c1, 0, 0, 0);
        }
#pragma unroll
        for (int r = 0; r < 4; ++r) {
            size_t n = (size_t)(nb16 + kg * 4 + r);
            out[n * OUT_F + o0 + arow]      = c0[r] + b2a;
            out[n * OUT_F + o0 + 16 + arow] = c1[r] + b2b;
        }
    }
}

extern "C" void kernel_launch(void* const* d_in, const int* in_sizes, int n_in,
                              void* d_out, int out_size, void* d_ws, size_t ws_size,
                              hipStream_t stream)
{
    const float* x    = (const float*)d_in[0];
    const int*   ei   = (const int*)  d_in[1];
    const float* ea   = (const float*)d_in[2];
    const float* w1   = (const float*)d_in[3];
    const float* b1   = (const float*)d_in[4];
    const float* w2   = (const float*)d_in[5];
    const float* b2   = (const float*)d_in[6];
    const float* eps  = (const float*)d_in[7];
    const float* nw1  = (const float*)d_in[8];
    const float* nb1  = (const float*)d_in[9];
    const float* nw2  = (const float*)d_in[10];
    const float* nb2  = (const float*)d_in[11];
    float* out = (float*)d_out;

    // ws layout (bytes): ~35.0 MB <= proven 38.4 MB
    char* ws = (char*)d_ws;
    int*            bcnt    = (int*)           (ws + 0);         // 784
    int*            offsets = (int*)           (ws + 4096);      // 200,000
    uint2*          brec    = (uint2*)         (ws + 212992);    // 8,028,160
    unsigned char*  bd8     = (unsigned char*) (ws + 8241152);   // 1,003,520
    uint2*          sorted  = (uint2*)         (ws + 9244672);   // 6,400,000
    _Float16*       v       = (_Float16*)      (ws + 15644672);  // 19,200,000

    // xh lives in d_out (6.4 MB of 25.6 MB); dead before k_mlp overwrites
    _Float16* xh = (_Float16*)d_out;

    hipMemsetAsync(bcnt, 0, NBUCK * sizeof(int), stream);

    k_part  <<<EDGEB + XCVT_BLOCKS, 256, 0, stream>>>(
        x, xh, ei, ea, w1, b1, w2, b2, bcnt, brec, bd8);
    k_sortb <<<NBUCK,       512, 0, stream>>>(bcnt, brec, bd8, offsets, sorted);
    k_gather<<<N_NODES / 8, 256, 0, stream>>>(sorted, offsets, xh, eps, v);
    k_mlp   <<<768,         256, 0, stream>>>(v, nw1, nb1, nw2, nb2, out);
}

// Round 28
// 90.820 us; speedup vs baseline: 1.2842x; 1.2842x over previous
//
#include <hip/hip_runtime.h>
#include <math.h>

#define N_NODES 50000
#define E_EDGES 800000
#define D_FEAT  64
#define C_CH    3
#define H_HID   8
#define OUT_F   128
#define CD      192              // C*D
#define NTILES  (N_NODES / 16)   // 3125 exact
#define XCVT_BLOCKS (N_NODES * D_FEAT / 4 / 256)   // 3125
#define EDGEB   ((E_EDGES + 1023) / 1024)          // 782 (4 edges/thread)
#define NBUCK   196              // buckets of 256 nodes (dst>>8)
#define BCAP    5120             // per-bucket capacity (mean 4096, +16 sigma)

typedef _Float16 half8 __attribute__((ext_vector_type(8)));
typedef _Float16 half4 __attribute__((ext_vector_type(4)));
typedef float f32x4 __attribute__((ext_vector_type(4)));

__device__ __forceinline__ float lrelu(float v) { return v >= 0.f ? v : 0.01f * v; }

__device__ __forceinline__ unsigned short f2h_bits(float f) {
    _Float16 h = (_Float16)f;
    unsigned short b;
    __builtin_memcpy(&b, &h, 2);
    return b;
}
__device__ __forceinline__ float h2f_bits(unsigned b) {
    unsigned short s = (unsigned short)b;
    _Float16 h;
    __builtin_memcpy(&h, &s, 2);
    return (float)h;
}

__device__ __forceinline__ float edge_mlp(
    float a, const float* __restrict__ w1, const float* __restrict__ b1,
    const float* __restrict__ w2, float b2c, int c)
{
    float s = 0.f;
#pragma unroll
    for (int h = 0; h < H_HID; ++h) {
        float t = fmaf(a, w1[c * H_HID + h], b1[c * H_HID + h]);
        t = (t >= 0.f) ? t : 0.01f * t;               // leaky_relu
        s = fmaf(t, w2[c * H_HID + h], s);
    }
    s += b2c;
    return (s > 0.f) ? s : expm1f(s);                 // elu
}

// --- K1: {edge MLP + coarse-bucket partition (LDS int hist)} + {x->f16} -----
// NO per-edge global atomics: per-edge rank via native LDS ds_add; ONE global
// cursor atomic per (block,bucket). Edge blocks first; xcvt blocks backfill.
__global__ __launch_bounds__(256) void k_part(
    const float* __restrict__ x, _Float16* __restrict__ xh,
    const int* __restrict__ ei, const float* __restrict__ ea,
    const float* __restrict__ w1, const float* __restrict__ b1,
    const float* __restrict__ w2, const float* __restrict__ b2,
    int* __restrict__ bcnt, uint2* __restrict__ brec,
    unsigned char* __restrict__ bd8)
{
    if (blockIdx.x >= EDGEB) {
        int i = (blockIdx.x - EDGEB) * 256 + threadIdx.x;
        float4 f = ((const float4*)x)[i];
        half4 h;
        h[0] = (_Float16)f.x; h[1] = (_Float16)f.y;
        h[2] = (_Float16)f.z; h[3] = (_Float16)f.w;
        *(half4*)(xh + (size_t)i * 4) = h;
        return;
    }
    __shared__ int hist[256];
    __shared__ int gbase[256];

    const int tid = threadIdx.x;
    const int e0  = blockIdx.x * 1024 + tid * 4;
    const int* dstp = ei + E_EDGES;
    const float b20 = b2[0], b21 = b2[1], b22 = b2[2];

    hist[tid] = 0;
    __syncthreads();

    int   sv[4], de[4];
    float av[4];
    if (e0 + 3 < E_EDGES) {
        int4   s4 = *(const int4*)(ei + e0);
        int4   d4 = *(const int4*)(dstp + e0);
        float4 a4 = *(const float4*)(ea + e0);
        sv[0]=s4.x; sv[1]=s4.y; sv[2]=s4.z; sv[3]=s4.w;
        de[0]=d4.x; de[1]=d4.y; de[2]=d4.z; de[3]=d4.w;
        av[0]=a4.x; av[1]=a4.y; av[2]=a4.z; av[3]=a4.w;
    } else {
#pragma unroll
        for (int j = 0; j < 4; ++j) {
            int e = e0 + j;
            sv[j] = (e < E_EDGES) ? ei[e]   : 0;
            de[j] = (e < E_EDGES) ? dstp[e] : -1;
            av[j] = (e < E_EDGES) ? ea[e]   : 0.f;
        }
    }

    int bk[4], lr[4];
#pragma unroll
    for (int j = 0; j < 4; ++j) {
        if (de[j] >= 0) {
            bk[j] = de[j] >> 8;
            lr[j] = atomicAdd(&hist[bk[j]], 1);   // native LDS int atomic
        } else bk[j] = -1;
    }
    __syncthreads();
    if (tid < NBUCK && hist[tid]) gbase[tid] = atomicAdd(bcnt + tid, hist[tid]);
    __syncthreads();

#pragma unroll
    for (int j = 0; j < 4; ++j) {
        if (bk[j] >= 0) {
            float w0 = edge_mlp(av[j], w1, b1, w2, b20, 0);
            float wA = edge_mlp(av[j], w1, b1, w2, b21, 1);
            float wB = edge_mlp(av[j], w1, b1, w2, b22, 2);
            uint2 r;
            r.x = (unsigned)sv[j] | ((unsigned)f2h_bits(w0) << 16);
            r.y = (unsigned)f2h_bits(wA) | ((unsigned)f2h_bits(wB) << 16);
            int pos = gbase[bk[j]] + lr[j];
            brec[(size_t)bk[j] * BCAP + pos] = r;
            bd8 [(size_t)bk[j] * BCAP + pos] = (unsigned char)(de[j] & 255);
        }
    }
}

// --- K2: per-bucket fine sort (LDS) + DIRECT offsets emission ---------------
// 512 threads per bucket block; scan phases use threads 0..255.
__global__ __launch_bounds__(512) void k_sortb(
    const int* __restrict__ bcnt, const uint2* __restrict__ brec,
    const unsigned char* __restrict__ bd8,
    int* __restrict__ offsets, uint2* __restrict__ sorted)
{
    __shared__ int sc[256];
    __shared__ int nodeh[256];
    __shared__ int pfx[256];
    __shared__ int cursor[256];
    __shared__ unsigned char s8[BCAP];

    const int tid = threadIdx.x;
    const int b   = blockIdx.x;

    if (tid < 256) {
        sc[tid]    = (tid < NBUCK) ? bcnt[tid] : 0;
        nodeh[tid] = 0;
    }
    __syncthreads();
    for (int off = 1; off < 256; off <<= 1) {
        int t = 0;
        if (tid < 256 && tid >= off) t = sc[tid - off];
        __syncthreads();
        if (tid < 256) sc[tid] += t;
        __syncthreads();
    }
    const int base = (b == 0) ? 0 : sc[b - 1];
    const int cnt  = bcnt[b];

    for (int i = tid; i < cnt; i += 512) {
        unsigned char d = bd8[(size_t)b * BCAP + i];
        s8[i] = d;
        atomicAdd(&nodeh[d], 1);
    }
    __syncthreads();

    if (tid < 256) pfx[tid] = nodeh[tid];
    __syncthreads();
    for (int off = 1; off < 256; off <<= 1) {
        int t = 0;
        if (tid < 256 && tid >= off) t = pfx[tid - off];
        __syncthreads();
        if (tid < 256) pfx[tid] += t;
        __syncthreads();
    }
    if (tid < 256) {
        int excl = pfx[tid] - nodeh[tid];
        cursor[tid] = excl;
        int n = b * 256 + tid;
        if (n < N_NODES) offsets[n] = base + excl;   // coalesced
    }
    __syncthreads();

    for (int i = tid; i < cnt; i += 512) {
        uint2 r = brec[(size_t)b * BCAP + i];
        int pos = atomicAdd(&cursor[s8[i]], 1);
        sorted[base + pos] = r;
    }
}

// --- K3: gather (f16 x rows) + residual (from xh) -> v[N][192] f16 ----------
__global__ __launch_bounds__(256) void k_gather(
    const uint2* __restrict__ sorted, const int* __restrict__ offsets,
    const _Float16* __restrict__ xh, const float* __restrict__ eps,
    _Float16* __restrict__ v)
{
    const int n    = blockIdx.x * 4 + (threadIdx.x >> 6);   // grid = N/4 exact
    const int lane = threadIdx.x & 63;

    const int start = offsets[n];
    const int end   = (n + 1 < N_NODES) ? offsets[n + 1] : E_EDGES;

    float xn = (float)xh[(size_t)n * D_FEAT + lane];

    float a0 = 0.f, a1 = 0.f, a2 = 0.f;
    float b0 = 0.f, b1 = 0.f, b2 = 0.f;
    float c0 = 0.f, c1 = 0.f, c2 = 0.f;
    float d0 = 0.f, d1 = 0.f, d2 = 0.f;

    for (int base = start; base < end; base += 64) {
        const int m = min(64, end - base);
        uint2 rec = make_uint2(0u, 0u);
        if (lane < m) rec = sorted[base + lane];     // coalesced 8B
        int j = 0;
        for (; j + 4 <= m; j += 4) {
            unsigned rxA = (unsigned)__shfl((int)rec.x, j);
            unsigned ryA = (unsigned)__shfl((int)rec.y, j);
            unsigned rxB = (unsigned)__shfl((int)rec.x, j + 1);
            unsigned ryB = (unsigned)__shfl((int)rec.y, j + 1);
            unsigned rxC = (unsigned)__shfl((int)rec.x, j + 2);
            unsigned ryC = (unsigned)__shfl((int)rec.y, j + 2);
            unsigned rxD = (unsigned)__shfl((int)rec.x, j + 3);
            unsigned ryD = (unsigned)__shfl((int)rec.y, j + 3);
            float xA = (float)xh[(size_t)(rxA & 0xFFFFu) * D_FEAT + lane];
            float xB = (float)xh[(size_t)(rxB & 0xFFFFu) * D_FEAT + lane];
            float xC = (float)xh[(size_t)(rxC & 0xFFFFu) * D_FEAT + lane];
            float xD = (float)xh[(size_t)(rxD & 0xFFFFu) * D_FEAT + lane];
            a0 = fmaf(h2f_bits(rxA >> 16),     xA, a0);
            a1 = fmaf(h2f_bits(ryA & 0xFFFFu), xA, a1);
            a2 = fmaf(h2f_bits(ryA >> 16),     xA, a2);
            b0 = fmaf(h2f_bits(rxB >> 16),     xB, b0);
            b1 = fmaf(h2f_bits(ryB & 0xFFFFu), xB, b1);
            b2 = fmaf(h2f_bits(ryB >> 16),     xB, b2);
            c0 = fmaf(h2f_bits(rxC >> 16),     xC, c0);
            c1 = fmaf(h2f_bits(ryC & 0xFFFFu), xC, c1);
            c2 = fmaf(h2f_bits(ryC >> 16),     xC, c2);
            d0 = fmaf(h2f_bits(rxD >> 16),     xD, d0);
            d1 = fmaf(h2f_bits(ryD & 0xFFFFu), xD, d1);
            d2 = fmaf(h2f_bits(ryD >> 16),     xD, d2);
        }
        for (; j < m; ++j) {
            unsigned rx0 = (unsigned)__shfl((int)rec.x, j);
            unsigned ry0 = (unsigned)__shfl((int)rec.y, j);
            float xa = (float)xh[(size_t)(rx0 & 0xFFFFu) * D_FEAT + lane];
            a0 = fmaf(h2f_bits(rx0 >> 16),     xa, a0);
            a1 = fmaf(h2f_bits(ry0 & 0xFFFFu), xa, a1);
            a2 = fmaf(h2f_bits(ry0 >> 16),     xa, a2);
        }
    }
    a0 += b0 + c0 + d0;
    a1 += b1 + c1 + d1;
    a2 += b2 + c2 + d2;

    _Float16* vr = v + (size_t)n * CD;
    vr[lane]       = (_Float16)(a0 + (1.f + eps[0]) * xn);
    vr[64 + lane]  = (_Float16)(a1 + (1.f + eps[1]) * xn);
    vr[128 + lane] = (_Float16)(a2 + (1.f + eps[2]) * xn);
}

// --- K4: MLP1(lrelu) + MLP2 via f16 MFMA ------------------------------------
__global__ __launch_bounds__(256) void k_mlp(
    const _Float16* __restrict__ v,
    const float* __restrict__ nw1, const float* __restrict__ nb1,
    const float* __restrict__ nw2, const float* __restrict__ nb2,
    float* __restrict__ out)
{
    __shared__ _Float16 vtile[16][CD + 8];     // stride 400B (16B mult)
    __shared__ _Float16 htile[16][OUT_F + 8];  // stride 272B (16B mult)

    const int tid  = threadIdx.x;
    const int lane = tid & 63;
    const int wid  = tid >> 6;
    const int arow = lane & 15;
    const int kg   = lane >> 4;
    const int o0   = wid * 32;

    half8 w1f[6][2], w2f[4][2];
#pragma unroll
    for (int kk = 0; kk < 6; ++kk)
#pragma unroll
        for (int nt = 0; nt < 2; ++nt) {
            half8 f;
            int colb = o0 + nt * 16 + arow;
            int kb = kk * 32 + kg * 8;
#pragma unroll
            for (int j = 0; j < 8; ++j)
                f[j] = (_Float16)nw1[(size_t)(kb + j) * OUT_F + colb];
            w1f[kk][nt] = f;
        }
#pragma unroll
    for (int kk = 0; kk < 4; ++kk)
#pragma unroll
        for (int nt = 0; nt < 2; ++nt) {
            half8 f;
            int colb = o0 + nt * 16 + arow;
            int kb = kk * 32 + kg * 8;
#pragma unroll
            for (int j = 0; j < 8; ++j)
                f[j] = (_Float16)nw2[(size_t)(kb + j) * OUT_F + colb];
            w2f[kk][nt] = f;
        }

    const float b1a = nb1[o0 + arow],      b1b = nb1[o0 + 16 + arow];
    const float b2a = nb2[o0 + arow],      b2b = nb2[o0 + 16 + arow];

    for (int t = blockIdx.x; t < NTILES; t += gridDim.x) {
        const int nb16 = t * 16;
        __syncthreads();

        for (int i = tid; i < 16 * (CD / 8); i += 256) {    // 384 chunks
            int row = i / (CD / 8), c8 = i % (CD / 8);
            *(half8*)&vtile[row][c8 * 8] =
                *(const half8*)(v + (size_t)(nb16 + row) * CD + c8 * 8);
        }
        __syncthreads();

        f32x4 acc0 = {0.f, 0.f, 0.f, 0.f}, acc1 = {0.f, 0.f, 0.f, 0.f};
#pragma unroll
        for (int kk = 0; kk < 6; ++kk) {
            half8 a = *(const half8*)&vtile[arow][kk * 32 + kg * 8];
            acc0 = __builtin_amdgcn_mfma_f32_16x16x32_f16(a, w1f[kk][0], acc0, 0, 0, 0);
            acc1 = __builtin_amdgcn_mfma_f32_16x16x32_f16(a, w1f[kk][1], acc1, 0, 0, 0);
        }
#pragma unroll
        for (int r = 0; r < 4; ++r) {
            int hr = kg * 4 + r;
            htile[hr][o0 + arow]      = (_Float16)lrelu(acc0[r] + b1a);
            htile[hr][o0 + 16 + arow] = (_Float16)lrelu(acc1[r] + b1b);
        }
        __syncthreads();

        f32x4 c0 = {0.f, 0.f, 0.f, 0.f}, c1 = {0.f, 0.f, 0.f, 0.f};
#pragma unroll
        for (int kk = 0; kk < 4; ++kk) {
            half8 a = *(const half8*)&htile[arow][kk * 32 + kg * 8];
            c0 = __builtin_amdgcn_mfma_f32_16x16x32_f16(a, w2f[kk][0], c0, 0, 0, 0);
            c1 = __builtin_amdgcn_mfma_f32_16x16x32_f16(a, w2f[kk][1], c1, 0, 0, 0);
        }
#pragma unroll
        for (int r = 0; r < 4; ++r) {
            size_t n = (size_t)(nb16 + kg * 4 + r);
            out[n * OUT_F + o0 + arow]      = c0[r] + b2a;
            out[n * OUT_F + o0 + 16 + arow] = c1[r] + b2b;
        }
    }
}

extern "C" void kernel_launch(void* const* d_in, const int* in_sizes, int n_in,
                              void* d_out, int out_size, void* d_ws, size_t ws_size,
                              hipStream_t stream)
{
    const float* x    = (const float*)d_in[0];
    const int*   ei   = (const int*)  d_in[1];
    const float* ea   = (const float*)d_in[2];
    const float* w1   = (const float*)d_in[3];
    const float* b1   = (const float*)d_in[4];
    const float* w2   = (const float*)d_in[5];
    const float* b2   = (const float*)d_in[6];
    const float* eps  = (const float*)d_in[7];
    const float* nw1  = (const float*)d_in[8];
    const float* nb1  = (const float*)d_in[9];
    const float* nw2  = (const float*)d_in[10];
    const float* nb2  = (const float*)d_in[11];
    float* out = (float*)d_out;

    // ws layout (bytes): ~35.0 MB <= proven 38.4 MB
    char* ws = (char*)d_ws;
    int*            bcnt    = (int*)           (ws + 0);         // 784
    int*            offsets = (int*)           (ws + 4096);      // 200,000
    uint2*          brec    = (uint2*)         (ws + 212992);    // 8,028,160
    unsigned char*  bd8     = (unsigned char*) (ws + 8241152);   // 1,003,520
    uint2*          sorted  = (uint2*)         (ws + 9244672);   // 6,400,000
    _Float16*       v       = (_Float16*)      (ws + 15644672);  // 19,200,000

    // xh lives in d_out (6.4 MB of 25.6 MB); dead before k_mlp overwrites
    // (proven safe in rounds 14/18/19/22/24/26)
    _Float16* xh = (_Float16*)d_out;

    hipMemsetAsync(bcnt, 0, NBUCK * sizeof(int), stream);

    k_part  <<<EDGEB + XCVT_BLOCKS, 256, 0, stream>>>(
        x, xh, ei, ea, w1, b1, w2, b2, bcnt, brec, bd8);
    k_sortb <<<NBUCK,       512, 0, stream>>>(bcnt, brec, bd8, offsets, sorted);
    k_gather<<<N_NODES / 4, 256, 0, stream>>>(sorted, offsets, xh, eps, v);
    k_mlp   <<<768,         256, 0, stream>>>(v, nw1, nb1, nw2, nb2, out);
}